// Round 5
// baseline (43.400 us; speedup 1.0000x reference)
//
#include <hip/hip_runtime.h>

// NormalizedBoxCenterEncoder  B=32, N=100000, M=500  (all f32 + int32 matches)
// d_out: targets (B,N,4) then masks (B,N,4), flat f32.
// R5: thread-adjacent 4-item assignment — vectorized float4/int4 loads of
// samples/matches (was 4 scalar loads each). Anchors/stores become 16B/lane
// at 64B lane-stride; betting L1/L2 merges them to full lines.

#define BB 32
#define NN 100000
#define MM 500
#define TOTAL (BB * NN)          // 3,200,000 — divisible by 1024

typedef float f32x4 __attribute__((ext_vector_type(4)));
typedef int   i32x4 __attribute__((ext_vector_type(4)));

__global__ __launch_bounds__(256) void nbce_kernel(
    const float*  __restrict__ samples,
    const int*    __restrict__ matches,
    const f32x4*  __restrict__ anchors,
    const f32x4*  __restrict__ refs,
    f32x4*        __restrict__ targets,
    f32x4*        __restrict__ masks)
{
    int t  = blockIdx.x * 256 + threadIdx.x;   // one thread : 4 consecutive items
    int i0 = t * 4;

    // NN % 4 == 0 → items i0..i0+3 share the same batch b
    int b = i0 / NN;                            // magic-mul
    const f32x4* __restrict__ refb = refs + b * MM;

    f32x4 s4 = *(const f32x4*)(samples + i0);   // 16B vector load
    i32x4 m4 = *(const i32x4*)(matches + i0);   // 16B vector load

#pragma unroll
    for (int u = 0; u < 4; ++u) {
        int i = i0 + u;

        int idx = m4[u];
        idx = idx < 0 ? 0 : idx;                // jnp.clip(matches, 0)

        f32x4 rb = refb[idx];                   // 8KB slice, L1-resident gather
        f32x4 ab = anchors[i];                  // 16B/lane, 64B lane-stride

        float aw = ab.z - ab.x;
        float ah = ab.w - ab.y;
        float ax = ab.x + aw * 0.5f;
        float ay = ab.y + ah * 0.5f;

        float gw = rb.z - rb.x;
        float gh = rb.w - rb.y;
        float gx = rb.x + gw * 0.5f;
        float gy = rb.y + gh * 0.5f;

        // MEANS = 0; STDS = (.1,.1,.2,.2) -> x10, x10, x5, x5
        float t0 = ((gx - ax) / aw) * 10.0f;
        float t1 = ((gy - ay) / ah) * 10.0f;
        float t2 = __logf(gw / aw) * 5.0f;
        float t3 = __logf(gh / ah) * 5.0f;

        bool  pos = s4[u] > 0.5f;               // samples are +-1
        float m   = pos ? 1.0f : 0.0f;

        f32x4 tv;
        tv.x = pos ? t0 : 0.0f;
        tv.y = pos ? t1 : 0.0f;
        tv.z = pos ? t2 : 0.0f;
        tv.w = pos ? t3 : 0.0f;
        f32x4 mv = {m, m, m, m};

        targets[i] = tv;
        masks[i]   = mv;
    }
}

extern "C" void kernel_launch(void* const* d_in, const int* in_sizes, int n_in,
                              void* d_out, int out_size, void* d_ws, size_t ws_size,
                              hipStream_t stream)
{
    const float* samples = (const float*)d_in[0];
    const int*   matches = (const int*)d_in[1];
    const f32x4* anchors = (const f32x4*)d_in[2];
    const f32x4* refs    = (const f32x4*)d_in[3];

    float* out = (float*)d_out;
    f32x4* targets = (f32x4*)out;                         // B*N*4 floats
    f32x4* masks   = (f32x4*)(out + (size_t)TOTAL * 4);   // next B*N*4 floats

    int grid = TOTAL / (256 * 4);   // 3125 blocks, covers exactly
    nbce_kernel<<<grid, 256, 0, stream>>>(samples, matches, anchors, refs,
                                          targets, masks);
}

// Round 6
// 31.985 us; speedup vs baseline: 1.3569x; 1.3569x over previous
//
#include <hip/hip_runtime.h>

// NormalizedBoxCenterEncoder  B=32, N=100000, M=500  (all f32 + int32 matches)
// d_out: targets (B,N,4) then masks (B,N,4), flat f32.
// R6: R4's proven wave-stride stream pattern + LDS-staged refs gather.
// Each block stages the 8KB refs slice for its batch (16KB if it straddles
// a batch boundary — 31 of 6250 blocks) and gathers via ds_read_b128,
// taking the ~50-lines/instr splintered gather off the L1/VMEM path.

#define BB 32
#define NN 100000
#define MM 500
#define TOTAL (BB * NN)          // 3,200,000
#define IPB 512                  // items per block: 256 threads x 2 wave-stride

typedef float f32x4 __attribute__((ext_vector_type(4)));

__global__ __launch_bounds__(256) void nbce_kernel(
    const float*  __restrict__ samples,
    const int*    __restrict__ matches,
    const f32x4*  __restrict__ anchors,
    const f32x4*  __restrict__ refs,
    f32x4*        __restrict__ targets,
    f32x4*        __restrict__ masks)
{
    __shared__ f32x4 lref[2 * MM];           // 16 KB: slice b0 at [0,500), b1 at [500,1000)

    int base = blockIdx.x * IPB;
    int b0 = base / NN;
    int b1 = (base + IPB - 1) / NN;

    // stage slice b0 (coalesced 16B/lane, 1KB/instr)
    const f32x4* __restrict__ s0 = refs + b0 * MM;
    for (int k = threadIdx.x; k < MM; k += 256) lref[k] = s0[k];
    if (b1 != b0) {                          // block-uniform branch, 31/6250 blocks
        const f32x4* __restrict__ s1 = refs + b1 * MM;
        for (int k = threadIdx.x; k < MM; k += 256) lref[MM + k] = s1[k];
    }
    __syncthreads();

#pragma unroll
    for (int u = 0; u < 2; ++u) {
        int i = base + threadIdx.x + u * 256;

        int b = i / NN;                      // magic-mul
        int idx = matches[i];                // coalesced 4B
        idx = idx < 0 ? 0 : idx;             // jnp.clip(matches, 0)
        int off = (b != b0) ? MM : 0;

        f32x4 rb = lref[off + idx];          // LDS gather (ds_read_b128)
        f32x4 ab = anchors[i];               // coalesced 16B
        float s  = samples[i];               // coalesced 4B

        float aw = ab.z - ab.x;
        float ah = ab.w - ab.y;
        float ax = ab.x + aw * 0.5f;
        float ay = ab.y + ah * 0.5f;

        float gw = rb.z - rb.x;
        float gh = rb.w - rb.y;
        float gx = rb.x + gw * 0.5f;
        float gy = rb.y + gh * 0.5f;

        // MEANS = 0; STDS = (.1,.1,.2,.2) -> x10, x10, x5, x5
        float t0 = ((gx - ax) / aw) * 10.0f;
        float t1 = ((gy - ay) / ah) * 10.0f;
        float t2 = __logf(gw / aw) * 5.0f;
        float t3 = __logf(gh / ah) * 5.0f;

        bool  pos = s > 0.5f;                // samples are +-1
        float m   = pos ? 1.0f : 0.0f;

        f32x4 tv;
        tv.x = pos ? t0 : 0.0f;
        tv.y = pos ? t1 : 0.0f;
        tv.z = pos ? t2 : 0.0f;
        tv.w = pos ? t3 : 0.0f;
        f32x4 mv = {m, m, m, m};

        targets[i] = tv;                     // coalesced 16B stores
        masks[i]   = mv;
    }
}

extern "C" void kernel_launch(void* const* d_in, const int* in_sizes, int n_in,
                              void* d_out, int out_size, void* d_ws, size_t ws_size,
                              hipStream_t stream)
{
    const float* samples = (const float*)d_in[0];
    const int*   matches = (const int*)d_in[1];
    const f32x4* anchors = (const f32x4*)d_in[2];
    const f32x4* refs    = (const f32x4*)d_in[3];

    float* out = (float*)d_out;
    f32x4* targets = (f32x4*)out;                         // B*N*4 floats
    f32x4* masks   = (f32x4*)(out + (size_t)TOTAL * 4);   // next B*N*4 floats

    int grid = TOTAL / IPB;   // 6250 blocks, covers exactly
    nbce_kernel<<<grid, 256, 0, stream>>>(samples, matches, anchors, refs,
                                          targets, masks);
}